// Round 1
// baseline (1077.765 us; speedup 1.0000x reference)
//
#include <hip/hip_runtime.h>
#include <hip/hip_bf16.h>
#include <math.h>
#include <stdint.h>

#define E_   64
#define CAP_ 1024
#define D_   512
#define H_   2048

typedef short s8v __attribute__((ext_vector_type(8)));
typedef float f4v __attribute__((ext_vector_type(4)));

// fp32 -> bf16 round-to-nearest-even (no NaN concern for this data)
__device__ __forceinline__ short f2bf(float f) {
  unsigned u = __float_as_uint(f);
  u += 0x7fffu + ((u >> 16) & 1u);
  return (short)(u >> 16);
}

// async global->LDS, 16B per lane; lds dest = wave-uniform base + lane*16
__device__ __forceinline__ void gll16(const void* g, const void* l) {
  __builtin_amdgcn_global_load_lds(
      (__attribute__((address_space(1))) void*)(uintptr_t)g,
      (__attribute__((address_space(3))) void*)(uintptr_t)l, 16, 0, 0);
}

// -------- straight fp32 -> bf16 convert (x) --------
__global__ __launch_bounds__(256) void convk(const float* __restrict__ in,
                                             short* __restrict__ out, int n4) {
  int i = blockIdx.x * 256 + threadIdx.x;
  if (i >= n4) return;
  float4 v = ((const float4*)in)[i];
  short4 s;
  s.x = f2bf(v.x); s.y = f2bf(v.y); s.z = f2bf(v.z); s.w = f2bf(v.w);
  ((short4*)out)[i] = s;
}

// -------- transpose-convert: in[e][R][C] f32 -> out[e][C][R] bf16 --------
// grid (C/64, R/64, E), block 256
__global__ __launch_bounds__(256) void tconvk(const float* __restrict__ in,
                                              short* __restrict__ out, int R, int C) {
  __shared__ float t[64][65];
  const int e = blockIdx.z;
  const int r0 = blockIdx.y * 64, c0 = blockIdx.x * 64;
  const float* pin = in + (size_t)e * R * C;
  short* pout = out + (size_t)e * R * C;
  const int tc = threadIdx.x & 63, tr = threadIdx.x >> 6;
#pragma unroll
  for (int i = 0; i < 16; i++) {
    int r = tr + i * 4;
    t[tc][r] = pin[(size_t)(r0 + r) * C + c0 + tc];
  }
  __syncthreads();
#pragma unroll
  for (int i = 0; i < 16; i++) {
    int cc = tr + i * 4;
    pout[(size_t)(c0 + cc) * R + r0 + tc] = f2bf(t[cc][tc]);
  }
}

// -------- bf16 MFMA GEMM, m97 structure --------
// A   : [E][M][K] bf16 row-major (k-contig)
// Bt  : [E][N][K] bf16 row-major (k-contig)  (i.e. B transposed)
// C = A*B (+bias), GEMM1: +GELU -> bf16 h; GEMM2: +mask -> fp32 y
// grid (N/128, M/128, E), block 256 (4 waves, each 64x64 = 4x4 16x16x32 frags)
template <int M, int N, int K, bool SECOND>
__global__ __launch_bounds__(256)
void ffn_gemm(const short* __restrict__ Aall, const short* __restrict__ Btall,
              const float* __restrict__ bias, const int* __restrict__ valid,
              short* __restrict__ hOut, float* __restrict__ yOut) {
  __shared__ __align__(16) short sA[128 * 32];
  __shared__ __align__(16) short sB[128 * 32];

  const int e   = blockIdx.z;
  const int m0  = blockIdx.y * 128;
  const int n0  = blockIdx.x * 128;
  const int vl  = valid[e];
  const int tid = threadIdx.x;
  const int l   = tid & 63;
  const int w   = tid >> 6;

  if (m0 >= vl) {
    // fully-masked row block: GEMM1 skips (h never read); GEMM2 zero-fills y
    if (SECOND) {
      float4 z = make_float4(0.f, 0.f, 0.f, 0.f);
      float* yb = yOut + (size_t)e * M * N;
      for (int i = tid; i < 128 * 128 / 4; i += 256) {
        int r = i >> 5, c4 = i & 31;
        *(float4*)&yb[(size_t)(m0 + r) * N + n0 + c4 * 4] = z;
      }
    }
    return;
  }

  const short* Ae = Aall  + (size_t)e * M * K;
  const short* Be = Btall + (size_t)e * N * K;

  // staging: wave w stages tile rows [w*32, w*32+32), 2 issues x 16 rows
  const int srow = w * 32 + (l >> 2);
  const int scol = (l & 3) * 8;
  const short* gA = Ae + (size_t)(m0 + srow) * K + scol;
  const short* gB = Be + (size_t)(n0 + srow) * K + scol;
  const short* lA = &sA[w * 32 * 32];
  const short* lB = &sB[w * 32 * 32];

  const int wm = (w >> 1) * 64;   // wave's 64x64 sub-tile
  const int wn = (w & 1) * 64;
  const int fr = (l & 15) * 32 + (l >> 4) * 8;  // frag: row=lane&15, k=quad*8

  f4v acc[4][4];
#pragma unroll
  for (int a = 0; a < 4; a++)
#pragma unroll
    for (int b = 0; b < 4; b++)
      acc[a][b] = f4v{0.f, 0.f, 0.f, 0.f};

  const int KT = K / 32;
  for (int kt = 0; kt < KT; kt++) {
    __syncthreads();
    gll16(gA,           lA);
    gll16(gA + 16 * K,  lA + 16 * 32);
    gll16(gB,           lB);
    gll16(gB + 16 * K,  lB + 16 * 32);
    gA += 32; gB += 32;
    __syncthreads();

    s8v af[4], bfr[4];
#pragma unroll
    for (int i = 0; i < 4; i++)
      af[i] = *(const s8v*)&sA[(wm + i * 16) * 32 + fr];
#pragma unroll
    for (int i = 0; i < 4; i++)
      bfr[i] = *(const s8v*)&sB[(wn + i * 16) * 32 + fr];
#pragma unroll
    for (int a = 0; a < 4; a++)
#pragma unroll
      for (int b = 0; b < 4; b++)
        acc[a][b] = __builtin_amdgcn_mfma_f32_16x16x32_bf16(af[a], bfr[b], acc[a][b], 0, 0, 0);
  }

  // epilogue: C/D layout col=lane&15, row=quad*4+reg
  const int rbase = m0 + wm + (l >> 4) * 4;
  const int cbase = n0 + wn + (l & 15);
  const float* be = bias + (size_t)e * N;
  if (!SECOND) {
    short* hb = hOut + (size_t)e * M * N;
#pragma unroll
    for (int b = 0; b < 4; b++) {
      int col = cbase + b * 16;
      float bv = be[col];
#pragma unroll
      for (int a = 0; a < 4; a++) {
#pragma unroll
        for (int r = 0; r < 4; r++) {
          int row = rbase + a * 16 + r;
          float v = acc[a][b][r] + bv;
          v = v * 0.5f * (1.0f + erff(v * 0.70710678118f));  // exact-erf GELU
          hb[(size_t)row * N + col] = f2bf(v);
        }
      }
    }
  } else {
    float* yb = yOut + (size_t)e * M * N;
#pragma unroll
    for (int b = 0; b < 4; b++) {
      int col = cbase + b * 16;
      float bv = be[col];
#pragma unroll
      for (int a = 0; a < 4; a++) {
#pragma unroll
        for (int r = 0; r < 4; r++) {
          int row = rbase + a * 16 + r;
          float v = acc[a][b][r] + bv;
          yb[(size_t)row * N + col] = (row < vl) ? v : 0.0f;
        }
      }
    }
  }
}

extern "C" void kernel_launch(void* const* d_in, const int* in_sizes, int n_in,
                              void* d_out, int out_size, void* d_ws, size_t ws_size,
                              hipStream_t stream) {
  (void)in_sizes; (void)n_in; (void)out_size; (void)ws_size;
  const float* x  = (const float*)d_in[0];
  const int*   vl = (const int*)d_in[1];
  const float* w1 = (const float*)d_in[2];
  const float* b1 = (const float*)d_in[3];
  const float* w2 = (const float*)d_in[4];
  const float* b2 = (const float*)d_in[5];
  float* y = (float*)d_out;

  // workspace layout (bf16 shorts): x | w1^T | w2^T | h   = 604 MB total
  short* xb  = (short*)d_ws;
  short* w1t = xb  + (size_t)E_ * CAP_ * D_;   //  67.1 MB
  short* w2t = w1t + (size_t)E_ * D_ * H_;     // 134.2 MB
  short* hb  = w2t + (size_t)E_ * H_ * D_;     // 134.2 MB (h: 268.4 MB)

  // 1) x fp32 -> bf16
  int n4 = E_ * CAP_ * D_ / 4;
  convk<<<dim3(n4 / 256), dim3(256), 0, stream>>>(x, xb, n4);
  // 2) w1 [E][D][H] -> w1t [E][H][D] bf16
  tconvk<<<dim3(H_ / 64, D_ / 64, E_), dim3(256), 0, stream>>>(w1, w1t, D_, H_);
  // 3) w2 [E][H][D] -> w2t [E][D][H] bf16
  tconvk<<<dim3(D_ / 64, H_ / 64, E_), dim3(256), 0, stream>>>(w2, w2t, H_, D_);
  // 4) h = gelu(x @ w1 + b1)   [E][CAP][H] bf16
  hipLaunchKernelGGL((ffn_gemm<CAP_, H_, D_, false>),
                     dim3(H_ / 128, CAP_ / 128, E_), dim3(256), 0, stream,
                     xb, w1t, b1, vl, hb, (float*)nullptr);
  // 5) y = mask(h @ w2 + b2)   [E][CAP][D] fp32
  hipLaunchKernelGGL((ffn_gemm<CAP_, D_, H_, true>),
                     dim3(D_ / 128, CAP_ / 128, E_), dim3(256), 0, stream,
                     hb, w2t, b2, vl, (short*)nullptr, y);
}